// Round 11
// baseline (371.255 us; speedup 1.0000x reference)
//
#include <hip/hip_runtime.h>

#define D 64
// BUCKET_SHIFT 9 (512 rows/bucket): binA run length = chunk/nbuck ~28 edges,
// low partial-line write amp (R11/R12 evidence: binA time tracks run length,
// not occupancy).
#define BUCKET_SHIFT 9
#define ROWS_PER_BUCKET 512
#define NBUCK_MAX 1024
#define BINA_CHUNK 8192
#define BINA_THREADS 512
// key packing in tmp: [lr:13][col:19] in low u32, val f32 in high u32.
#define COL_BITS 19
#define COL_MASK ((1u << COL_BITS) - 1u)

typedef unsigned int u32;
typedef unsigned long long u64;

static inline char* align16(char* p) {
    return (char*)(((uintptr_t)p + 15) & ~(uintptr_t)15);
}

// bf16x2 helpers (packed pair in one u32; low ushort = even element)
__device__ __forceinline__ float bflo(u32 p) { return __uint_as_float(p << 16); }
__device__ __forceinline__ float bfhi(u32 p) { return __uint_as_float(p & 0xFFFF0000u); }
__device__ __forceinline__ u32 pack_bf16x2(float a, float b) {
    u32 ua = __float_as_uint(a);
    u32 ub = __float_as_uint(b);
    ua = (ua + 0x7FFFu + ((ua >> 16) & 1u)) >> 16;   // RNE
    ub = (ub + 0x7FFFu + ((ub >> 16) & 1u)) >> 16;
    return ua | (ub << 16);
}

// ---------------- init ----------------

__global__ void lg_to_bf16(const float4* __restrict__ user, const float4* __restrict__ item,
                           uint2* __restrict__ dst, int user_vec4, int total_vec4) {
    int i = blockIdx.x * blockDim.x + threadIdx.x;
    if (i >= total_vec4) return;
    float4 v = (i < user_vec4) ? user[i] : item[i - user_vec4];
    dst[i] = make_uint2(pack_bf16x2(v.x, v.y), pack_bf16x2(v.z, v.w));
}

// ---------------- two-level bucket sort ----------------
// R13: slab allocation (cap = avg + 1024 ~ 11 sigma), no pre-histogram.
// R18: binB2 additionally sorts the 512 rows of each bucket by DEGREE and
// emits edges in that order + a perm[] the pulls iterate by. Fixes the
// intra-wave straggler problem (8 rows/wave, Poisson(16) degrees: wave
// rounds = max of 8 ~ 3 vs ~2.2 when degree-uniform; R17 occupancy-time 42%).
// Edges stay in the bucket's L2-local window, so binA/binB2 write-amp
// properties are unchanged.

// Pass A: LDS hist -> one global atomic per (block,bucket) to reserve a run
// in the bucket's slab -> direct global scatter.
__global__ void lg_binA(const int* __restrict__ rows, const int* __restrict__ cols,
                        const float* __restrict__ vals, int* __restrict__ bucketCursor,
                        u64* __restrict__ tmp, int nnz, int nbuck, int cap) {
    __shared__ int hist[NBUCK_MAX];
    __shared__ int base[NBUCK_MAX];
    int tid = threadIdx.x;
    int bstart = blockIdx.x * BINA_CHUNK;
    int bend = min(bstart + BINA_CHUNK, nnz);

    for (int i = tid; i < nbuck; i += BINA_THREADS) hist[i] = 0;
    __syncthreads();
    for (int e = bstart + tid; e < bend; e += BINA_THREADS)
        atomicAdd(&hist[rows[e] >> BUCKET_SHIFT], 1);
    __syncthreads();
    for (int b = tid; b < nbuck; b += BINA_THREADS) {
        int c = hist[b];
        base[b] = (c > 0) ? (b * cap + atomicAdd(&bucketCursor[b], c)) : 0;
        hist[b] = 0;   // reuse as local cursor
    }
    __syncthreads();
    for (int e = bstart + tid; e < bend; e += BINA_THREADS) {
        int r = rows[e];
        int b = r >> BUCKET_SHIFT;
        int pos = base[b] + atomicAdd(&hist[b], 1);
        // overflow tripwire (never taken for uniform rows; memory safety)
        if (pos < (b + 1) * cap) {
            u32 key = ((u32)(r & (ROWS_PER_BUCKET - 1)) << COL_BITS) | (u32)cols[e];
            u64 packed = (u64)key | ((u64)__float_as_uint(vals[e]) << 32);
            tmp[pos] = packed;
        }
    }
}

// Tiny scan over per-bucket counts -> CSR bucket bases. 1 block.
__global__ void lg_cscan(const int* __restrict__ bucketCursor, int* __restrict__ bucketOffs,
                         int nbuck, int cap) {
    __shared__ int s[1024];
    int t = threadIdx.x;
    int v = (t < nbuck) ? min(bucketCursor[t], cap) : 0;
    s[t] = v;
    __syncthreads();
    #pragma unroll
    for (int off = 1; off < 1024; off <<= 1) {
        int x = (t >= off) ? s[t - off] : 0;
        __syncthreads();
        s[t] += x;
        __syncthreads();
    }
    if (t < nbuck) bucketOffs[t] = s[t] - v;
    if (t == 1023) bucketOffs[nbuck] = s[1023];
}

// Pass B2 (+degree sort): one block per bucket (512 rows). Per-row count,
// counting-sort rows by degree, emit degree-ordered per-row offsets
// (offsS/offsE, non-monotone vs row id), perm[slot]=row, then scatter edges
// into the bucket's L2-local window in that order.
__global__ void lg_binB2(const int* __restrict__ bucketCursor, const int* __restrict__ bucketOffs,
                         const u64* __restrict__ tmp,
                         int* __restrict__ offsS, int* __restrict__ offsE,
                         int* __restrict__ perm,
                         int2* __restrict__ edges, int n, int cap) {
    __shared__ int h[ROWS_PER_BUCKET];
    __shared__ int s[ROWS_PER_BUCKET];
    __shared__ int cur[ROWS_PER_BUCKET];
    __shared__ int sdeg[ROWS_PER_BUCKET];
    __shared__ int dcnt[64];
    __shared__ int dbase[64];
    int bucket = blockIdx.x;
    int row0 = bucket << BUCKET_SHIFT;
    int tid = threadIdx.x;
    size_t tbase = (size_t)bucket * (size_t)cap;
    int cnt = min(bucketCursor[bucket], cap);
    int cbase = bucketOffs[bucket];

    h[tid] = 0;
    if (tid < 64) dcnt[tid] = 0;
    __syncthreads();
    for (int e = tid; e < cnt; e += 512)
        atomicAdd(&h[(u32)((u32)tmp[tbase + e]) >> COL_BITS], 1);
    __syncthreads();
    int deg = h[tid];
    int dc = min(deg, 63);
    int rid = atomicAdd(&dcnt[dc], 1);   // rank within degree bin
    __syncthreads();
    if (tid == 0) {
        int a = 0;
        #pragma unroll
        for (int i = 0; i < 64; ++i) { int t = dcnt[i]; dbase[i] = a; a += t; }
    }
    __syncthreads();
    int rank = dbase[dc] + rid;          // degree-sorted position in bucket
    sdeg[rank] = deg;
    __syncthreads();
    // inclusive scan of sdeg (by position)
    int v = sdeg[tid];
    s[tid] = v;
    __syncthreads();
    #pragma unroll
    for (int off = 1; off < 512; off <<= 1) {
        int x = (tid >= off) ? s[tid - off] : 0;
        __syncthreads();
        s[tid] += x;
        __syncthreads();
    }
    int myOff = cbase + s[rank] - deg;   // exclusive prefix at my rank
    int r = row0 + tid;
    offsS[r] = myOff;
    offsE[r] = myOff + deg;
    perm[row0 + rank] = r;
    cur[tid] = myOff;
    __syncthreads();
    for (int e = tid; e < cnt; e += 512) {
        u64 p = tmp[tbase + e];
        u32 key = (u32)p;
        int lr = key >> COL_BITS;
        int col = (int)(key & COL_MASK);
        int pos = atomicAdd(&cur[lr], 1);
        edges[pos] = make_int2(col, (int)(u32)(p >> 32));
    }
}

// ---------------- fallback CSR build ----------------

__global__ void lg_hist(const int* __restrict__ rows, int* __restrict__ counts, int nnz) {
    int e = blockIdx.x * blockDim.x + threadIdx.x;
    if (e >= nnz) return;
    atomicAdd(&counts[rows[e]], 1);
}

__global__ void lg_scan1(const int* __restrict__ counts, int* __restrict__ offsets,
                         int* __restrict__ offsE, int* __restrict__ perm,
                         int* __restrict__ cursor, int n) {
    const int T = 1024;
    int t = threadIdx.x;
    int chunk = (n + T - 1) / T;
    int start = t * chunk;
    int end = min(start + chunk, n);
    int sum = 0;
    for (int i = start; i < end; ++i) sum += counts[i];
    __shared__ int sdata[T];
    sdata[t] = sum;
    __syncthreads();
    #pragma unroll
    for (int off = 1; off < T; off <<= 1) {
        int v = (t >= off) ? sdata[t - off] : 0;
        __syncthreads();
        sdata[t] += v;
        __syncthreads();
    }
    int offset = sdata[t] - sum;
    for (int i = start; i < end; ++i) {
        int c = counts[i];
        offsets[i] = offset;
        offsE[i] = offset + c;
        perm[i] = i;
        cursor[i] = offset;
        offset += c;
    }
    if (t == T - 1) offsets[n] = sdata[T - 1];
}

__global__ void lg_fill(const int* __restrict__ rows, const int* __restrict__ cols,
                        const float* __restrict__ vals, int* __restrict__ cursor,
                        u64* __restrict__ edges, int nnz) {
    int e = blockIdx.x * blockDim.x + threadIdx.x;
    if (e >= nnz) return;
    int pos = atomicAdd(&cursor[rows[e]], 1);
    u64 packed = (u64)(u32)cols[e] | ((u64)__float_as_uint(vals[e]) << 32);
    edges[pos] = packed;
}

// ---------------- pull SpMM (bf16 gather, fp32 accumulate) ----------------
// R17: 8-lane sub owns one row, lane q loads 16B (uint4 = dims 8q..8q+7);
// gather = 1KB/instr, 8-deep load clause. R18: rows iterated via degree-
// sorted perm[] so each wave's 8 rows have ~equal degree (kills the
// straggler rounds; R17 occupancy-time was 42%).

__global__ void lg_pull_bf16(const int* __restrict__ offsS, const int* __restrict__ offsE,
                             const int* __restrict__ perm,
                             const int2* __restrict__ edges,
                             const u32* __restrict__ src,
                             u32* __restrict__ nxt, int n, int nslots) {
    int slot = blockIdx.x * 32 + (threadIdx.x >> 3);
    if (slot >= nslots) return;
    int row = perm[slot];
    if (row >= n) return;
    int q = threadIdx.x & 7;

    int beg = offsS[row];
    int end = offsE[row];
    float4 acc0 = make_float4(0.f, 0.f, 0.f, 0.f);
    float4 acc1 = make_float4(0.f, 0.f, 0.f, 0.f);

    int j = beg;
    for (; j + 8 <= end; j += 8) {
        int2 e[8];
        #pragma unroll
        for (int k = 0; k < 8; ++k) e[k] = edges[j + k];
        uint4 g[8];
        #pragma unroll
        for (int k = 0; k < 8; ++k)
            g[k] = ((const uint4*)(src + (size_t)e[k].x * 32))[q];
        #pragma unroll
        for (int k = 0; k < 8; ++k) {
            float v = __int_as_float(e[k].y);
            acc0.x += v * bflo(g[k].x);
            acc0.y += v * bfhi(g[k].x);
            acc0.z += v * bflo(g[k].y);
            acc0.w += v * bfhi(g[k].y);
            acc1.x += v * bflo(g[k].z);
            acc1.y += v * bfhi(g[k].z);
            acc1.z += v * bflo(g[k].w);
            acc1.w += v * bfhi(g[k].w);
        }
    }
    for (; j + 4 <= end; j += 4) {
        int2 e[4];
        #pragma unroll
        for (int k = 0; k < 4; ++k) e[k] = edges[j + k];
        uint4 g[4];
        #pragma unroll
        for (int k = 0; k < 4; ++k)
            g[k] = ((const uint4*)(src + (size_t)e[k].x * 32))[q];
        #pragma unroll
        for (int k = 0; k < 4; ++k) {
            float v = __int_as_float(e[k].y);
            acc0.x += v * bflo(g[k].x);
            acc0.y += v * bfhi(g[k].x);
            acc0.z += v * bflo(g[k].y);
            acc0.w += v * bfhi(g[k].y);
            acc1.x += v * bflo(g[k].z);
            acc1.y += v * bfhi(g[k].z);
            acc1.z += v * bflo(g[k].w);
            acc1.w += v * bfhi(g[k].w);
        }
    }
    for (; j < end; ++j) {
        int2 e = edges[j];
        uint4 g = ((const uint4*)(src + (size_t)e.x * 32))[q];
        float v = __int_as_float(e.y);
        acc0.x += v * bflo(g.x);
        acc0.y += v * bfhi(g.x);
        acc0.z += v * bflo(g.y);
        acc0.w += v * bfhi(g.y);
        acc1.x += v * bflo(g.z);
        acc1.y += v * bfhi(g.z);
        acc1.z += v * bflo(g.w);
        acc1.w += v * bfhi(g.w);
    }

    // norm reduce across the 8 lanes of this sub
    float ss = acc0.x * acc0.x + acc0.y * acc0.y + acc0.z * acc0.z + acc0.w * acc0.w
             + acc1.x * acc1.x + acc1.y * acc1.y + acc1.z * acc1.z + acc1.w * acc1.w;
    ss += __shfl_xor(ss, 1, 64);
    ss += __shfl_xor(ss, 2, 64);
    ss += __shfl_xor(ss, 4, 64);
    float inv = 1.0f / fmaxf(sqrtf(ss), 1e-12f);

    uint4 o;
    o.x = pack_bf16x2(acc0.x * inv, acc0.y * inv);
    o.y = pack_bf16x2(acc0.z * inv, acc0.w * inv);
    o.z = pack_bf16x2(acc1.x * inv, acc1.y * inv);
    o.w = pack_bf16x2(acc1.z * inv, acc1.w * inv);
    ((uint4*)(nxt + (size_t)row * 32))[q] = o;
}

// Final pull: layer-3 propagation fused with the 4-layer mean.
__global__ void lg_pull_final(const int* __restrict__ offsS, const int* __restrict__ offsE,
                              const int* __restrict__ perm,
                              const int2* __restrict__ edges,
                              const u32* __restrict__ src,      // e2 table
                              const float4* __restrict__ user, const float4* __restrict__ item,
                              int nU,
                              const u32* __restrict__ e1b,
                              float4* __restrict__ out, int n, int nslots) {
    int slot = blockIdx.x * 32 + (threadIdx.x >> 3);
    if (slot >= nslots) return;
    int row = perm[slot];
    if (row >= n) return;
    int q = threadIdx.x & 7;

    int beg = offsS[row];
    int end = offsE[row];
    float4 acc0 = make_float4(0.f, 0.f, 0.f, 0.f);
    float4 acc1 = make_float4(0.f, 0.f, 0.f, 0.f);

    int j = beg;
    for (; j + 8 <= end; j += 8) {
        int2 e[8];
        #pragma unroll
        for (int k = 0; k < 8; ++k) e[k] = edges[j + k];
        uint4 g[8];
        #pragma unroll
        for (int k = 0; k < 8; ++k)
            g[k] = ((const uint4*)(src + (size_t)e[k].x * 32))[q];
        #pragma unroll
        for (int k = 0; k < 8; ++k) {
            float v = __int_as_float(e[k].y);
            acc0.x += v * bflo(g[k].x);
            acc0.y += v * bfhi(g[k].x);
            acc0.z += v * bflo(g[k].y);
            acc0.w += v * bfhi(g[k].y);
            acc1.x += v * bflo(g[k].z);
            acc1.y += v * bfhi(g[k].z);
            acc1.z += v * bflo(g[k].w);
            acc1.w += v * bfhi(g[k].w);
        }
    }
    for (; j + 4 <= end; j += 4) {
        int2 e[4];
        #pragma unroll
        for (int k = 0; k < 4; ++k) e[k] = edges[j + k];
        uint4 g[4];
        #pragma unroll
        for (int k = 0; k < 4; ++k)
            g[k] = ((const uint4*)(src + (size_t)e[k].x * 32))[q];
        #pragma unroll
        for (int k = 0; k < 4; ++k) {
            float v = __int_as_float(e[k].y);
            acc0.x += v * bflo(g[k].x);
            acc0.y += v * bfhi(g[k].x);
            acc0.z += v * bflo(g[k].y);
            acc0.w += v * bfhi(g[k].y);
            acc1.x += v * bflo(g[k].z);
            acc1.y += v * bfhi(g[k].z);
            acc1.z += v * bflo(g[k].w);
            acc1.w += v * bfhi(g[k].w);
        }
    }
    for (; j < end; ++j) {
        int2 e = edges[j];
        uint4 g = ((const uint4*)(src + (size_t)e.x * 32))[q];
        float v = __int_as_float(e.y);
        acc0.x += v * bflo(g.x);
        acc0.y += v * bfhi(g.x);
        acc0.z += v * bflo(g.y);
        acc0.w += v * bfhi(g.y);
        acc1.x += v * bflo(g.z);
        acc1.y += v * bfhi(g.z);
        acc1.z += v * bflo(g.w);
        acc1.w += v * bfhi(g.w);
    }

    float ss = acc0.x * acc0.x + acc0.y * acc0.y + acc0.z * acc0.z + acc0.w * acc0.w
             + acc1.x * acc1.x + acc1.y * acc1.y + acc1.z * acc1.z + acc1.w * acc1.w;
    ss += __shfl_xor(ss, 1, 64);
    ss += __shfl_xor(ss, 2, 64);
    ss += __shfl_xor(ss, 4, 64);
    float inv = 1.0f / fmaxf(sqrtf(ss), 1e-12f);

    float4 aLo, aHi;
    if (row < nU) {
        aLo = user[(size_t)row * 16 + 2 * q];
        aHi = user[(size_t)row * 16 + 2 * q + 1];
    } else {
        aLo = item[(size_t)(row - nU) * 16 + 2 * q];
        aHi = item[(size_t)(row - nU) * 16 + 2 * q + 1];
    }
    uint4 b1 = ((const uint4*)(e1b + (size_t)row * 32))[q];
    uint4 b2 = ((const uint4*)(src + (size_t)row * 32))[q];
    float4 r0, r1;
    r0.x = (aLo.x + bflo(b1.x) + bflo(b2.x) + acc0.x * inv) * 0.25f;
    r0.y = (aLo.y + bfhi(b1.x) + bfhi(b2.x) + acc0.y * inv) * 0.25f;
    r0.z = (aLo.z + bflo(b1.y) + bflo(b2.y) + acc0.z * inv) * 0.25f;
    r0.w = (aLo.w + bfhi(b1.y) + bfhi(b2.y) + acc0.w * inv) * 0.25f;
    r1.x = (aHi.x + bflo(b1.z) + bflo(b2.z) + acc1.x * inv) * 0.25f;
    r1.y = (aHi.y + bfhi(b1.z) + bfhi(b2.z) + acc1.y * inv) * 0.25f;
    r1.z = (aHi.z + bflo(b1.w) + bflo(b2.w) + acc1.z * inv) * 0.25f;
    r1.w = (aHi.w + bfhi(b1.w) + bfhi(b2.w) + acc1.w * inv) * 0.25f;
    out[(size_t)row * 16 + 2 * q] = r0;
    out[(size_t)row * 16 + 2 * q + 1] = r1;
}

// ---------------- fallback (atomic-scatter fp32 path) ----------------

__global__ void lg_init(const float4* __restrict__ user, const float4* __restrict__ item,
                        float4* __restrict__ cur, float4* __restrict__ sum,
                        int user_vec4, int total_vec4) {
    int i = blockIdx.x * blockDim.x + threadIdx.x;
    if (i >= total_vec4) return;
    float4 v = (i < user_vec4) ? user[i] : item[i - user_vec4];
    cur[i] = v;
    sum[i] = v;
}

__global__ void lg_scatter(const int* __restrict__ rows, const int* __restrict__ cols,
                           const float* __restrict__ vals,
                           const float* __restrict__ cur, float* __restrict__ next,
                           int nnz) {
    int gid = blockIdx.x * blockDim.x + threadIdx.x;
    int e = gid >> 6;
    int d = gid & 63;
    if (e >= nnz) return;
    atomicAdd(&next[rows[e] * D + d], vals[e] * cur[cols[e] * D + d]);
}

__global__ void lg_norm_acc(float* __restrict__ emb, float* __restrict__ sum, int n) {
    int row = blockIdx.x * (blockDim.x >> 6) + (threadIdx.x >> 6);
    int d = threadIdx.x & 63;
    if (row >= n) return;
    int idx = row * D + d;
    float v = emb[idx];
    float ss = v * v;
    #pragma unroll
    for (int off = 32; off > 0; off >>= 1) ss += __shfl_xor(ss, off, 64);
    float out = v / fmaxf(sqrtf(ss), 1e-12f);
    emb[idx] = out;
    sum[idx] += out;
}

__global__ void lg_final(float4* __restrict__ out, int n4) {
    int i = blockIdx.x * blockDim.x + threadIdx.x;
    if (i >= n4) return;
    float4 s = out[i];
    out[i] = make_float4(s.x * 0.25f, s.y * 0.25f, s.z * 0.25f, s.w * 0.25f);
}

// ---------------- launch ----------------

extern "C" void kernel_launch(void* const* d_in, const int* in_sizes, int n_in,
                              void* d_out, int out_size, void* d_ws, size_t ws_size,
                              hipStream_t stream) {
    const float* user = (const float*)d_in[0];
    const float* item = (const float*)d_in[1];
    const float* vals = (const float*)d_in[2];
    const int*   rows = (const int*)d_in[3];
    const int*   cols = (const int*)d_in[4];

    const int nU  = in_sizes[0] / D;
    const int nI  = in_sizes[1] / D;
    const int N   = nU + nI;
    const int nnz = in_sizes[2];

    const size_t embElems = (size_t)N * D;
    const size_t embU32   = (size_t)N * 32;
    const int total4 = (int)(embElems / 4);
    float* out = (float*)d_out;

    const int nbuck = (N + ROWS_PER_BUCKET - 1) / ROWS_PER_BUCKET;
    const int padN = nbuck * ROWS_PER_BUCKET;     // >= N, bucket-padded rows
    // slab capacity: avg + 1024 (~11 sigma for uniform rows), 64-aligned
    int cap = (nnz + nbuck - 1) / nbuck + 1024;
    cap = (cap + 63) & ~63;

    // ws layout
    char* p = (char*)d_ws;
    u32* t0  = (u32*)p;           p = align16(p + embU32 * sizeof(u32));
    u32* e1b = (u32*)p;           p = align16(p + embU32 * sizeof(u32));
    u32* e2b = (u32*)p;           p = align16(p + embU32 * sizeof(u32));
    int* counts   = (int*)p;      p = align16(p + (size_t)N * sizeof(int));     // fallback only
    int* offsets  = (int*)p;      p = align16(p + (size_t)(padN + 1) * sizeof(int));
    int* offsE    = (int*)p;      p = align16(p + (size_t)padN * sizeof(int));
    int* perm     = (int*)p;      p = align16(p + (size_t)padN * sizeof(int));
    int* cursor   = (int*)p;      p = align16(p + (size_t)N * sizeof(int));     // fallback only
    int* bucketOffs = (int*)p;    p = align16(p + (NBUCK_MAX + 1) * sizeof(int));
    int* bucketCursor = (int*)p;  p = align16(p + NBUCK_MAX * sizeof(int));
    u64* edges    = (u64*)p;      p = align16(p + (size_t)nnz * sizeof(u64));
    size_t needNoTmp = (size_t)(p - (char*)d_ws);
    u64* tmp      = (u64*)p;      p = align16(p + (size_t)nbuck * (size_t)cap * sizeof(u64));
    size_t needBytes = (size_t)(p - (char*)d_ws);

    if (ws_size >= needNoTmp) {
        lg_to_bf16<<<(total4 + 255) / 256, 256, 0, stream>>>(
            (const float4*)user, (const float4*)item, (uint2*)t0, nU * D / 4, total4);

        int nslots;
        if (nbuck <= NBUCK_MAX && ws_size >= needBytes) {
            hipMemsetAsync(bucketCursor, 0, (size_t)nbuck * sizeof(int), stream);
            int ab = (nnz + BINA_CHUNK - 1) / BINA_CHUNK;
            lg_binA<<<ab, BINA_THREADS, 0, stream>>>(rows, cols, vals, bucketCursor,
                                                     tmp, nnz, nbuck, cap);
            lg_cscan<<<1, 1024, 0, stream>>>(bucketCursor, bucketOffs, nbuck, cap);
            lg_binB2<<<nbuck, 512, 0, stream>>>(bucketCursor, bucketOffs, tmp,
                                                offsets, offsE, perm,
                                                (int2*)edges, N, cap);
            nslots = padN;
        } else {
            hipMemsetAsync(counts, 0, (size_t)N * sizeof(int), stream);
            int eb = (nnz + 255) / 256;
            lg_hist<<<eb, 256, 0, stream>>>(rows, counts, nnz);
            lg_scan1<<<1, 1024, 0, stream>>>(counts, offsets, offsE, perm, cursor, N);
            lg_fill<<<eb, 256, 0, stream>>>(rows, cols, vals, cursor, edges, nnz);
            nslots = N;
        }

        // ---- layers 1,2 bf16; layer 3 fused with mean ----
        int rb = (nslots + 31) / 32;
        lg_pull_bf16<<<rb, 256, 0, stream>>>(offsets, offsE, perm, (const int2*)edges,
                                             t0,  e1b, N, nslots);
        lg_pull_bf16<<<rb, 256, 0, stream>>>(offsets, offsE, perm, (const int2*)edges,
                                             e1b, e2b, N, nslots);
        lg_pull_final<<<rb, 256, 0, stream>>>(offsets, offsE, perm, (const int2*)edges,
                                              e2b,
                                              (const float4*)user, (const float4*)item, nU,
                                              e1b, (float4*)out, N, nslots);
    } else {
        // fallback: fp32 atomic scatter
        float* buf0 = (float*)t0;
        float* buf1 = buf0 + embElems;
        float* sum  = out;
        lg_init<<<(total4 + 255) / 256, 256, 0, stream>>>(
            (const float4*)user, (const float4*)item,
            (float4*)buf0, (float4*)sum, nU * D / 4, total4);
        float* cur = buf0;
        float* nxt = buf1;
        for (int layer = 0; layer < 3; ++layer) {
            hipMemsetAsync(nxt, 0, embElems * sizeof(float), stream);
            int totThreads = nnz * 64;
            int blocks = (totThreads + 255) / 256;
            lg_scatter<<<blocks, 256, 0, stream>>>(rows, cols, vals, cur, nxt, nnz);
            lg_norm_acc<<<(N + 3) / 4, 256, 0, stream>>>(nxt, sum, N);
            float* t = cur; cur = nxt; nxt = t;
        }
        lg_final<<<(total4 + 255) / 256, 256, 0, stream>>>((float4*)sum, total4);
    }
}

// Round 13
// 351.948 us; speedup vs baseline: 1.0549x; 1.0549x over previous
//
#include <hip/hip_runtime.h>

#define D 64
// R19: BUCKET_SHIFT 10 (1024 rows/bucket, 147 slabs): binA run length =
// chunk/nbuck ~56 edges (448B) -- write-amp is binA's proven bottleneck
// (R11/R12: time tracks run length, not occupancy). binB2 keeps a balanced
// 294-block grid by processing HALF-buckets (512 rows each), re-reading the
// full slab (+19MB read, cheap) so no CU idles.
#define BUCKET_SHIFT 10
#define ROWS_PER_BUCKET 1024
#define NBUCK_MAX 1024
#define BINA_CHUNK 8192
#define BINA_THREADS 512
// key packing in tmp: [lr:10][col:19] in low u32 (col<2^19), val in high u32.
#define COL_BITS 19
#define COL_MASK ((1u << COL_BITS) - 1u)

typedef unsigned int u32;
typedef unsigned long long u64;

static inline char* align16(char* p) {
    return (char*)(((uintptr_t)p + 15) & ~(uintptr_t)15);
}

// bf16x2 helpers (packed pair in one u32; low ushort = even element)
__device__ __forceinline__ float bflo(u32 p) { return __uint_as_float(p << 16); }
__device__ __forceinline__ float bfhi(u32 p) { return __uint_as_float(p & 0xFFFF0000u); }
__device__ __forceinline__ u32 pack_bf16x2(float a, float b) {
    u32 ua = __float_as_uint(a);
    u32 ub = __float_as_uint(b);
    ua = (ua + 0x7FFFu + ((ua >> 16) & 1u)) >> 16;   // RNE
    ub = (ub + 0x7FFFu + ((ub >> 16) & 1u)) >> 16;
    return ua | (ub << 16);
}

// ---------------- init ----------------

__global__ void lg_to_bf16(const float4* __restrict__ user, const float4* __restrict__ item,
                           uint2* __restrict__ dst, int user_vec4, int total_vec4) {
    int i = blockIdx.x * blockDim.x + threadIdx.x;
    if (i >= total_vec4) return;
    float4 v = (i < user_vec4) ? user[i] : item[i - user_vec4];
    dst[i] = make_uint2(pack_bf16x2(v.x, v.y), pack_bf16x2(v.z, v.w));
}

// ---------------- two-level bucket sort ----------------
// R13: slab allocation (cap = avg + 12 sigma), no pre-histogram; lg_cscan
// (1 tiny block) scans slab counts into CSR bucket bases.

// Pass A: LDS hist -> one global atomic per (block,bucket) to reserve a run
// in the bucket's slab -> direct global scatter.
__global__ void lg_binA(const int* __restrict__ rows, const int* __restrict__ cols,
                        const float* __restrict__ vals, int* __restrict__ bucketCursor,
                        u64* __restrict__ tmp, int nnz, int nbuck, int cap) {
    __shared__ int hist[NBUCK_MAX];
    __shared__ int base[NBUCK_MAX];
    int tid = threadIdx.x;
    int bstart = blockIdx.x * BINA_CHUNK;
    int bend = min(bstart + BINA_CHUNK, nnz);

    for (int i = tid; i < nbuck; i += BINA_THREADS) hist[i] = 0;
    __syncthreads();
    for (int e = bstart + tid; e < bend; e += BINA_THREADS)
        atomicAdd(&hist[rows[e] >> BUCKET_SHIFT], 1);
    __syncthreads();
    for (int b = tid; b < nbuck; b += BINA_THREADS) {
        int c = hist[b];
        base[b] = (c > 0) ? (b * cap + atomicAdd(&bucketCursor[b], c)) : 0;
        hist[b] = 0;   // reuse as local cursor
    }
    __syncthreads();
    for (int e = bstart + tid; e < bend; e += BINA_THREADS) {
        int r = rows[e];
        int b = r >> BUCKET_SHIFT;
        int pos = base[b] + atomicAdd(&hist[b], 1);
        // overflow tripwire (never taken for uniform rows; memory safety)
        if (pos < (b + 1) * cap) {
            u32 key = ((u32)(r & (ROWS_PER_BUCKET - 1)) << COL_BITS) | (u32)cols[e];
            u64 packed = (u64)key | ((u64)__float_as_uint(vals[e]) << 32);
            tmp[pos] = packed;
        }
    }
}

// Tiny scan over per-bucket counts -> CSR bucket bases. 1 block.
__global__ void lg_cscan(const int* __restrict__ bucketCursor, int* __restrict__ bucketOffs,
                         int* __restrict__ offsets_end, int nbuck, int cap) {
    __shared__ int s[1024];
    int t = threadIdx.x;
    int v = (t < nbuck) ? min(bucketCursor[t], cap) : 0;
    s[t] = v;
    __syncthreads();
    #pragma unroll
    for (int off = 1; off < 1024; off <<= 1) {
        int x = (t >= off) ? s[t - off] : 0;
        __syncthreads();
        s[t] += x;
        __syncthreads();
    }
    if (t < nbuck) bucketOffs[t] = s[t] - v;
    if (t == 1023) {
        bucketOffs[nbuck] = s[1023];
        *offsets_end = s[1023];
    }
}

// Pass B2 (half-bucket): 2 blocks per slab, 512 threads. Block bb handles
// rows [half*512, half*512+512) of bucket bb>>1: reads the full slab,
// hists its own 512 rows, derives its CSR base (half1 = cnt - ownTotal),
// emits per-row CSR offsets and scatters its edges (L2-local window,
// single-writer lines).
__global__ void lg_binB2(const int* __restrict__ bucketCursor, const int* __restrict__ bucketOffs,
                         const u64* __restrict__ tmp,
                         int* __restrict__ offsets, int2* __restrict__ edges, int n, int cap) {
    __shared__ int h[512];
    __shared__ int s[512];
    __shared__ int cur[512];
    __shared__ int sTot;
    int bb = blockIdx.x;
    int bucket = bb >> 1;
    int half = bb & 1;
    int row0 = (bucket << BUCKET_SHIFT) + (half << 9);
    int tid = threadIdx.x;
    size_t tbase = (size_t)bucket * (size_t)cap;
    int cnt = min(bucketCursor[bucket], cap);

    h[tid] = 0;
    __syncthreads();
    for (int e = tid; e < cnt; e += 512) {
        u32 lr = (u32)((u32)tmp[tbase + e]) >> COL_BITS;   // 10-bit local row
        if ((int)(lr >> 9) == half) atomicAdd(&h[lr & 511], 1);
    }
    __syncthreads();
    int v = h[tid];
    s[tid] = v;
    __syncthreads();
    #pragma unroll
    for (int off = 1; off < 512; off <<= 1) {
        int x = (tid >= off) ? s[tid - off] : 0;
        __syncthreads();
        s[tid] += x;
        __syncthreads();
    }
    if (tid == 511) sTot = s[511];
    __syncthreads();
    int base = bucketOffs[bucket] + (half ? (cnt - sTot) : 0);
    int rowOff = base + s[tid] - v;
    int r = row0 + tid;
    if (r < n) offsets[r] = rowOff;
    cur[tid] = rowOff;
    __syncthreads();
    for (int e = tid; e < cnt; e += 512) {
        u64 p = tmp[tbase + e];
        u32 key = (u32)p;
        u32 lr = key >> COL_BITS;
        if ((int)(lr >> 9) == half) {
            int col = (int)(key & COL_MASK);
            int pos = atomicAdd(&cur[lr & 511], 1);
            edges[pos] = make_int2(col, (int)(u32)(p >> 32));
        }
    }
}

// ---------------- fallback CSR build ----------------

__global__ void lg_hist(const int* __restrict__ rows, int* __restrict__ counts, int nnz) {
    int e = blockIdx.x * blockDim.x + threadIdx.x;
    if (e >= nnz) return;
    atomicAdd(&counts[rows[e]], 1);
}

__global__ void lg_scan1(const int* __restrict__ counts, int* __restrict__ offsets,
                         int* __restrict__ cursor, int n) {
    const int T = 1024;
    int t = threadIdx.x;
    int chunk = (n + T - 1) / T;
    int start = t * chunk;
    int end = min(start + chunk, n);
    int sum = 0;
    for (int i = start; i < end; ++i) sum += counts[i];
    __shared__ int sdata[T];
    sdata[t] = sum;
    __syncthreads();
    #pragma unroll
    for (int off = 1; off < T; off <<= 1) {
        int v = (t >= off) ? sdata[t - off] : 0;
        __syncthreads();
        sdata[t] += v;
        __syncthreads();
    }
    int offset = sdata[t] - sum;
    for (int i = start; i < end; ++i) {
        int c = counts[i];
        offsets[i] = offset;
        cursor[i] = offset;
        offset += c;
    }
    if (t == T - 1) offsets[n] = sdata[T - 1];
}

__global__ void lg_fill(const int* __restrict__ rows, const int* __restrict__ cols,
                        const float* __restrict__ vals, int* __restrict__ cursor,
                        u64* __restrict__ edges, int nnz) {
    int e = blockIdx.x * blockDim.x + threadIdx.x;
    if (e >= nnz) return;
    int pos = atomicAdd(&cursor[rows[e]], 1);
    u64 packed = (u64)(u32)cols[e] | ((u64)__float_as_uint(vals[e]) << 32);
    edges[pos] = packed;
}

// ---------------- pull SpMM (bf16 gather, fp32 accumulate) ----------------
// R17 (proven best, 59.4us): 8-lane sub owns one row, lane q loads 16B
// (uint4 = dims 8q..8q+7); gather = 1KB/instr, 8-deep load clause. Pulls
// are fabric-bound on random 128B L3 reads (~3.7 TB/s ceiling): R14
// predication, R15 NT hints, R16 unroll-16, R18 degree-sort all FAILED.
// Do not touch.

__global__ void lg_pull_bf16(const int* __restrict__ offs, const int2* __restrict__ edges,
                             const u32* __restrict__ src,
                             u32* __restrict__ nxt, int n) {
    int row = blockIdx.x * 32 + (threadIdx.x >> 3);
    if (row >= n) return;
    int q = threadIdx.x & 7;

    int beg = offs[row];
    int end = offs[row + 1];
    float4 acc0 = make_float4(0.f, 0.f, 0.f, 0.f);
    float4 acc1 = make_float4(0.f, 0.f, 0.f, 0.f);

    int j = beg;
    for (; j + 8 <= end; j += 8) {
        int2 e[8];
        #pragma unroll
        for (int k = 0; k < 8; ++k) e[k] = edges[j + k];
        uint4 g[8];
        #pragma unroll
        for (int k = 0; k < 8; ++k)
            g[k] = ((const uint4*)(src + (size_t)e[k].x * 32))[q];
        #pragma unroll
        for (int k = 0; k < 8; ++k) {
            float v = __int_as_float(e[k].y);
            acc0.x += v * bflo(g[k].x);
            acc0.y += v * bfhi(g[k].x);
            acc0.z += v * bflo(g[k].y);
            acc0.w += v * bfhi(g[k].y);
            acc1.x += v * bflo(g[k].z);
            acc1.y += v * bfhi(g[k].z);
            acc1.z += v * bflo(g[k].w);
            acc1.w += v * bfhi(g[k].w);
        }
    }
    for (; j + 4 <= end; j += 4) {
        int2 e[4];
        #pragma unroll
        for (int k = 0; k < 4; ++k) e[k] = edges[j + k];
        uint4 g[4];
        #pragma unroll
        for (int k = 0; k < 4; ++k)
            g[k] = ((const uint4*)(src + (size_t)e[k].x * 32))[q];
        #pragma unroll
        for (int k = 0; k < 4; ++k) {
            float v = __int_as_float(e[k].y);
            acc0.x += v * bflo(g[k].x);
            acc0.y += v * bfhi(g[k].x);
            acc0.z += v * bflo(g[k].y);
            acc0.w += v * bfhi(g[k].y);
            acc1.x += v * bflo(g[k].z);
            acc1.y += v * bfhi(g[k].z);
            acc1.z += v * bflo(g[k].w);
            acc1.w += v * bfhi(g[k].w);
        }
    }
    for (; j < end; ++j) {
        int2 e = edges[j];
        uint4 g = ((const uint4*)(src + (size_t)e.x * 32))[q];
        float v = __int_as_float(e.y);
        acc0.x += v * bflo(g.x);
        acc0.y += v * bfhi(g.x);
        acc0.z += v * bflo(g.y);
        acc0.w += v * bfhi(g.y);
        acc1.x += v * bflo(g.z);
        acc1.y += v * bfhi(g.z);
        acc1.z += v * bflo(g.w);
        acc1.w += v * bfhi(g.w);
    }

    // norm reduce across the 8 lanes of this sub
    float ss = acc0.x * acc0.x + acc0.y * acc0.y + acc0.z * acc0.z + acc0.w * acc0.w
             + acc1.x * acc1.x + acc1.y * acc1.y + acc1.z * acc1.z + acc1.w * acc1.w;
    ss += __shfl_xor(ss, 1, 64);
    ss += __shfl_xor(ss, 2, 64);
    ss += __shfl_xor(ss, 4, 64);
    float inv = 1.0f / fmaxf(sqrtf(ss), 1e-12f);

    uint4 o;
    o.x = pack_bf16x2(acc0.x * inv, acc0.y * inv);
    o.y = pack_bf16x2(acc0.z * inv, acc0.w * inv);
    o.z = pack_bf16x2(acc1.x * inv, acc1.y * inv);
    o.w = pack_bf16x2(acc1.z * inv, acc1.w * inv);
    ((uint4*)(nxt + (size_t)row * 32))[q] = o;
}

// Final pull: layer-3 propagation fused with the 4-layer mean.
__global__ void lg_pull_final(const int* __restrict__ offs, const int2* __restrict__ edges,
                              const u32* __restrict__ src,      // e2 table
                              const float4* __restrict__ user, const float4* __restrict__ item,
                              int nU,
                              const u32* __restrict__ e1b,
                              float4* __restrict__ out, int n) {
    int row = blockIdx.x * 32 + (threadIdx.x >> 3);
    if (row >= n) return;
    int q = threadIdx.x & 7;

    int beg = offs[row];
    int end = offs[row + 1];
    float4 acc0 = make_float4(0.f, 0.f, 0.f, 0.f);
    float4 acc1 = make_float4(0.f, 0.f, 0.f, 0.f);

    int j = beg;
    for (; j + 8 <= end; j += 8) {
        int2 e[8];
        #pragma unroll
        for (int k = 0; k < 8; ++k) e[k] = edges[j + k];
        uint4 g[8];
        #pragma unroll
        for (int k = 0; k < 8; ++k)
            g[k] = ((const uint4*)(src + (size_t)e[k].x * 32))[q];
        #pragma unroll
        for (int k = 0; k < 8; ++k) {
            float v = __int_as_float(e[k].y);
            acc0.x += v * bflo(g[k].x);
            acc0.y += v * bfhi(g[k].x);
            acc0.z += v * bflo(g[k].y);
            acc0.w += v * bfhi(g[k].y);
            acc1.x += v * bflo(g[k].z);
            acc1.y += v * bfhi(g[k].z);
            acc1.z += v * bflo(g[k].w);
            acc1.w += v * bfhi(g[k].w);
        }
    }
    for (; j + 4 <= end; j += 4) {
        int2 e[4];
        #pragma unroll
        for (int k = 0; k < 4; ++k) e[k] = edges[j + k];
        uint4 g[4];
        #pragma unroll
        for (int k = 0; k < 4; ++k)
            g[k] = ((const uint4*)(src + (size_t)e[k].x * 32))[q];
        #pragma unroll
        for (int k = 0; k < 4; ++k) {
            float v = __int_as_float(e[k].y);
            acc0.x += v * bflo(g[k].x);
            acc0.y += v * bfhi(g[k].x);
            acc0.z += v * bflo(g[k].y);
            acc0.w += v * bfhi(g[k].y);
            acc1.x += v * bflo(g[k].z);
            acc1.y += v * bfhi(g[k].z);
            acc1.z += v * bflo(g[k].w);
            acc1.w += v * bfhi(g[k].w);
        }
    }
    for (; j < end; ++j) {
        int2 e = edges[j];
        uint4 g = ((const uint4*)(src + (size_t)e.x * 32))[q];
        float v = __int_as_float(e.y);
        acc0.x += v * bflo(g.x);
        acc0.y += v * bfhi(g.x);
        acc0.z += v * bflo(g.y);
        acc0.w += v * bfhi(g.y);
        acc1.x += v * bflo(g.z);
        acc1.y += v * bfhi(g.z);
        acc1.z += v * bflo(g.w);
        acc1.w += v * bfhi(g.w);
    }

    float ss = acc0.x * acc0.x + acc0.y * acc0.y + acc0.z * acc0.z + acc0.w * acc0.w
             + acc1.x * acc1.x + acc1.y * acc1.y + acc1.z * acc1.z + acc1.w * acc1.w;
    ss += __shfl_xor(ss, 1, 64);
    ss += __shfl_xor(ss, 2, 64);
    ss += __shfl_xor(ss, 4, 64);
    float inv = 1.0f / fmaxf(sqrtf(ss), 1e-12f);

    float4 aLo, aHi;
    if (row < nU) {
        aLo = user[(size_t)row * 16 + 2 * q];
        aHi = user[(size_t)row * 16 + 2 * q + 1];
    } else {
        aLo = item[(size_t)(row - nU) * 16 + 2 * q];
        aHi = item[(size_t)(row - nU) * 16 + 2 * q + 1];
    }
    uint4 b1 = ((const uint4*)(e1b + (size_t)row * 32))[q];
    uint4 b2 = ((const uint4*)(src + (size_t)row * 32))[q];
    float4 r0, r1;
    r0.x = (aLo.x + bflo(b1.x) + bflo(b2.x) + acc0.x * inv) * 0.25f;
    r0.y = (aLo.y + bfhi(b1.x) + bfhi(b2.x) + acc0.y * inv) * 0.25f;
    r0.z = (aLo.z + bflo(b1.y) + bflo(b2.y) + acc0.z * inv) * 0.25f;
    r0.w = (aLo.w + bfhi(b1.y) + bfhi(b2.y) + acc0.w * inv) * 0.25f;
    r1.x = (aHi.x + bflo(b1.z) + bflo(b2.z) + acc1.x * inv) * 0.25f;
    r1.y = (aHi.y + bfhi(b1.z) + bfhi(b2.z) + acc1.y * inv) * 0.25f;
    r1.z = (aHi.z + bflo(b1.w) + bflo(b2.w) + acc1.z * inv) * 0.25f;
    r1.w = (aHi.w + bfhi(b1.w) + bfhi(b2.w) + acc1.w * inv) * 0.25f;
    out[(size_t)row * 16 + 2 * q] = r0;
    out[(size_t)row * 16 + 2 * q + 1] = r1;
}

// ---------------- fallback (atomic-scatter fp32 path) ----------------

__global__ void lg_init(const float4* __restrict__ user, const float4* __restrict__ item,
                        float4* __restrict__ cur, float4* __restrict__ sum,
                        int user_vec4, int total_vec4) {
    int i = blockIdx.x * blockDim.x + threadIdx.x;
    if (i >= total_vec4) return;
    float4 v = (i < user_vec4) ? user[i] : item[i - user_vec4];
    cur[i] = v;
    sum[i] = v;
}

__global__ void lg_scatter(const int* __restrict__ rows, const int* __restrict__ cols,
                           const float* __restrict__ vals,
                           const float* __restrict__ cur, float* __restrict__ next,
                           int nnz) {
    int gid = blockIdx.x * blockDim.x + threadIdx.x;
    int e = gid >> 6;
    int d = gid & 63;
    if (e >= nnz) return;
    atomicAdd(&next[rows[e] * D + d], vals[e] * cur[cols[e] * D + d]);
}

__global__ void lg_norm_acc(float* __restrict__ emb, float* __restrict__ sum, int n) {
    int row = blockIdx.x * (blockDim.x >> 6) + (threadIdx.x >> 6);
    int d = threadIdx.x & 63;
    if (row >= n) return;
    int idx = row * D + d;
    float v = emb[idx];
    float ss = v * v;
    #pragma unroll
    for (int off = 32; off > 0; off >>= 1) ss += __shfl_xor(ss, off, 64);
    float out = v / fmaxf(sqrtf(ss), 1e-12f);
    emb[idx] = out;
    sum[idx] += out;
}

__global__ void lg_final(float4* __restrict__ out, int n4) {
    int i = blockIdx.x * blockDim.x + threadIdx.x;
    if (i >= n4) return;
    float4 s = out[i];
    out[i] = make_float4(s.x * 0.25f, s.y * 0.25f, s.z * 0.25f, s.w * 0.25f);
}

// ---------------- launch ----------------

extern "C" void kernel_launch(void* const* d_in, const int* in_sizes, int n_in,
                              void* d_out, int out_size, void* d_ws, size_t ws_size,
                              hipStream_t stream) {
    const float* user = (const float*)d_in[0];
    const float* item = (const float*)d_in[1];
    const float* vals = (const float*)d_in[2];
    const int*   rows = (const int*)d_in[3];
    const int*   cols = (const int*)d_in[4];

    const int nU  = in_sizes[0] / D;
    const int nI  = in_sizes[1] / D;
    const int N   = nU + nI;
    const int nnz = in_sizes[2];

    const size_t embElems = (size_t)N * D;
    const size_t embU32   = (size_t)N * 32;
    const int total4 = (int)(embElems / 4);
    float* out = (float*)d_out;

    const int nbuck = (N + ROWS_PER_BUCKET - 1) / ROWS_PER_BUCKET;
    // slab capacity: avg + 1536 (~12 sigma for uniform rows), 64-aligned
    int cap = (nnz + nbuck - 1) / nbuck + 1536;
    cap = (cap + 63) & ~63;

    // ws layout
    char* p = (char*)d_ws;
    u32* t0  = (u32*)p;           p = align16(p + embU32 * sizeof(u32));
    u32* e1b = (u32*)p;           p = align16(p + embU32 * sizeof(u32));
    u32* e2b = (u32*)p;           p = align16(p + embU32 * sizeof(u32));
    int* counts   = (int*)p;      p = align16(p + (size_t)N * sizeof(int));     // fallback only
    int* offsets  = (int*)p;      p = align16(p + (size_t)(N + 1) * sizeof(int));
    int* cursor   = (int*)p;      p = align16(p + (size_t)N * sizeof(int));     // fallback only
    int* bucketOffs = (int*)p;    p = align16(p + (NBUCK_MAX + 1) * sizeof(int));
    int* bucketCursor = (int*)p;  p = align16(p + NBUCK_MAX * sizeof(int));
    u64* edges    = (u64*)p;      p = align16(p + (size_t)nnz * sizeof(u64));
    size_t needNoTmp = (size_t)(p - (char*)d_ws);
    u64* tmp      = (u64*)p;      p = align16(p + (size_t)nbuck * (size_t)cap * sizeof(u64));
    size_t needBytes = (size_t)(p - (char*)d_ws);

    if (ws_size >= needNoTmp) {
        lg_to_bf16<<<(total4 + 255) / 256, 256, 0, stream>>>(
            (const float4*)user, (const float4*)item, (uint2*)t0, nU * D / 4, total4);

        if (nbuck <= NBUCK_MAX && ws_size >= needBytes) {
            hipMemsetAsync(bucketCursor, 0, (size_t)nbuck * sizeof(int), stream);
            int ab = (nnz + BINA_CHUNK - 1) / BINA_CHUNK;
            lg_binA<<<ab, BINA_THREADS, 0, stream>>>(rows, cols, vals, bucketCursor,
                                                     tmp, nnz, nbuck, cap);
            lg_cscan<<<1, 1024, 0, stream>>>(bucketCursor, bucketOffs,
                                             offsets + N, nbuck, cap);
            lg_binB2<<<nbuck * 2, 512, 0, stream>>>(bucketCursor, bucketOffs, tmp,
                                                    offsets, (int2*)edges, N, cap);
        } else {
            hipMemsetAsync(counts, 0, (size_t)N * sizeof(int), stream);
            int eb = (nnz + 255) / 256;
            lg_hist<<<eb, 256, 0, stream>>>(rows, counts, nnz);
            lg_scan1<<<1, 1024, 0, stream>>>(counts, offsets, cursor, N);
            lg_fill<<<eb, 256, 0, stream>>>(rows, cols, vals, cursor, edges, nnz);
        }

        // ---- layers 1,2 bf16; layer 3 fused with mean ----
        int rb = (N + 31) / 32;
        lg_pull_bf16<<<rb, 256, 0, stream>>>(offsets, (const int2*)edges, t0,  e1b, N);
        lg_pull_bf16<<<rb, 256, 0, stream>>>(offsets, (const int2*)edges, e1b, e2b, N);
        lg_pull_final<<<rb, 256, 0, stream>>>(offsets, (const int2*)edges, e2b,
                                              (const float4*)user, (const float4*)item, nU,
                                              e1b, (float4*)out, N);
    } else {
        // fallback: fp32 atomic scatter
        float* buf0 = (float*)t0;
        float* buf1 = buf0 + embElems;
        float* sum  = out;
        lg_init<<<(total4 + 255) / 256, 256, 0, stream>>>(
            (const float4*)user, (const float4*)item,
            (float4*)buf0, (float4*)sum, nU * D / 4, total4);
        float* cur = buf0;
        float* nxt = buf1;
        for (int layer = 0; layer < 3; ++layer) {
            hipMemsetAsync(nxt, 0, embElems * sizeof(float), stream);
            int totThreads = nnz * 64;
            int blocks = (totThreads + 255) / 256;
            lg_scatter<<<blocks, 256, 0, stream>>>(rows, cols, vals, cur, nxt, nnz);
            lg_norm_acc<<<(N + 3) / 4, 256, 0, stream>>>(nxt, sum, N);
            float* t = cur; cur = nxt; nxt = t;
        }
        lg_final<<<(total4 + 255) / 256, 256, 0, stream>>>((float4*)sum, total4);
    }
}